// Round 7
// baseline (859.777 us; speedup 1.0000x reference)
//
#include <hip/hip_runtime.h>
#include <cstdint>
#include <cstddef>

#define N_USER 100000
#define N_ITEM 50000
#define CDIM   128
#define NEDGE  600000
#define N_SEG  (N_ITEM + N_USER)          // item segments first, then user
#define NB_SCAN ((N_SEG + 255) / 256)     // 586 scan blocks

// XCD-sliced fill parameters (proven R1)
#define FILL_EPB 2048
#define FILL_NCHUNK ((NEDGE + FILL_EPB - 1) / FILL_EPB)   // 293
#define SLICE_DIV ((N_SEG + 7) / 8)

// Chunked gather: 4 column-chunks of 64B; items on XCD slot=chunk (0-3),
// users on slot=4+chunk. 4 nodes per 256-thr block.
#define GCH_IDX 25000                     // max idx per slot (users)
#define GCH (8 * GCH_IDX)                 // 200000 blocks

typedef __bf16 bf16_t;
typedef bf16_t bfvec8 __attribute__((ext_vector_type(8)));
typedef bf16_t bfvec4 __attribute__((ext_vector_type(4)));
typedef float  f32x4  __attribute__((ext_vector_type(4)));

#define LDW 136   // LDS row stride (elems) for 128-wide bf16 tiles

// ---------------------------------------------------------------------------
// One-time: transpose+cvt all 10 weight matrices to bf16 [n][k] in ws.
// ---------------------------------------------------------------------------
__global__ __launch_bounds__(256) void prep_weights(
    const float* __restrict__ W_init, const float* __restrict__ mlp_W,
    bf16_t* __restrict__ wtg)
{
    int m  = blockIdx.x >> 6;
    int it = blockIdx.x & 63;
    const float* src = (m < 2) ? (W_init + (size_t)m * 16384)
                               : (mlp_W + (size_t)(m - 2) * 16384);
    int e = it * 256 + threadIdx.x;      // e = n*128 + k
    int n = e >> 7, k = e & 127;
    wtg[(size_t)m * 16384 + e] = (bf16_t)src[k * 128 + n];
}

template <int NT>
static __device__ inline void stage_wbf(bf16_t* Wt, const bf16_t* __restrict__ Wg, int tid) {
    #pragma unroll
    for (int c = tid; c < 2048; c += NT) {
        int n = c >> 4, koff = (c & 15) * 8;
        *reinterpret_cast<bfvec8*>(&Wt[n * LDW + koff]) =
            *reinterpret_cast<const bfvec8*>(&Wg[n * 128 + koff]);
    }
}

// ---------------------------------------------------------------------------
// Init GEMM (proven R2): swapped MFMA operands, lane holds 4 consecutive
// output cols of its own row => vector stores. 512 thr.
// ---------------------------------------------------------------------------
__global__ __launch_bounds__(512) void gemm_init(
    const float* __restrict__ X,
    const bf16_t* __restrict__ Wg,     // pre-transposed bf16 [n][k]
    const float* __restrict__ B,
    bf16_t* __restrict__ Y, int M)
{
    __shared__ __align__(16) bf16_t Wt[128 * LDW];
    const int tid = threadIdx.x;
    stage_wbf<512>(Wt, Wg, tid);
    __syncthreads();

    const int wave = tid >> 6, lane = tid & 63;
    const int quad = lane >> 4, ln16 = lane & 15;
    const int row_l = wave * 16 + ln16;
    const int rowg = blockIdx.x * 128 + row_l;
    const int rowc = rowg < M ? rowg : 0;

    bfvec8 xb[4];
    const float* xp = X + (size_t)rowc * CDIM + quad * 8;
    #pragma unroll
    for (int kc = 0; kc < 4; ++kc) {
        f32x4 lo = *reinterpret_cast<const f32x4*>(xp + kc * 32);
        f32x4 hi = *reinterpret_cast<const f32x4*>(xp + kc * 32 + 4);
        #pragma unroll
        for (int j = 0; j < 4; ++j) {
            xb[kc][j]     = (bf16_t)lo[j];
            xb[kc][j + 4] = (bf16_t)hi[j];
        }
    }

    f32x4 acc[8];
    #pragma unroll
    for (int t = 0; t < 8; ++t) acc[t] = (f32x4){0.f, 0.f, 0.f, 0.f};
    #pragma unroll
    for (int t = 0; t < 8; ++t) {
        const bf16_t* wp = &Wt[(t * 16 + ln16) * LDW + quad * 8];
        #pragma unroll
        for (int kc = 0; kc < 4; ++kc) {
            bfvec8 wv = *reinterpret_cast<const bfvec8*>(wp + kc * 32);
            acc[t] = __builtin_amdgcn_mfma_f32_16x16x32_bf16(wv, xb[kc], acc[t], 0, 0, 0);
        }
    }

    if (rowg < M) {
        #pragma unroll
        for (int t = 0; t < 8; ++t) {
            f32x4 bv = *reinterpret_cast<const f32x4*>(&B[t * 16 + quad * 4]);
            bfvec4 o;
            #pragma unroll
            for (int r = 0; r < 4; ++r) o[r] = (bf16_t)(acc[t][r] + bv[r]);
            *reinterpret_cast<bfvec4*>(&Y[(size_t)rowg * CDIM + t * 16 + quad * 4]) = o;
        }
    }
}

// ---------------------------------------------------------------------------
// CSR build pieces (proven)
// ---------------------------------------------------------------------------
__global__ __launch_bounds__(256) void zero_i32(int* __restrict__ p, int n)
{
    int i = blockIdx.x * 256 + threadIdx.x;
    if (i < n) p[i] = 0;
}

__global__ __launch_bounds__(256) void hist_rank(
    const int* __restrict__ edge_ui, const int* __restrict__ edge_iu,
    int* __restrict__ deg, int2* __restrict__ rank2)
{
    int i = blockIdx.x * 256 + threadIdx.x;
    if (i >= NEDGE) return;
    int r0 = atomicAdd(&deg[edge_ui[NEDGE + i]], 1);
    int r1 = atomicAdd(&deg[N_ITEM + edge_iu[NEDGE + i]], 1);
    rank2[i] = make_int2(r0, r1);
}

__global__ __launch_bounds__(256) void block_scan(
    int* __restrict__ off, int* __restrict__ bsum, int n)
{
    __shared__ int sh[256];
    int tid = threadIdx.x;
    int i = blockIdx.x * 256 + tid;
    int v = (i < n) ? off[i] : 0;
    sh[tid] = v;
    __syncthreads();
    #pragma unroll
    for (int d = 1; d < 256; d <<= 1) {
        int t = (tid >= d) ? sh[tid - d] : 0;
        __syncthreads();
        sh[tid] += t;
        __syncthreads();
    }
    if (i < n) off[i] = sh[tid] - v;
    if (tid == 255) bsum[blockIdx.x] = sh[255];
}

__global__ __launch_bounds__(1024) void scan_bsums(int* __restrict__ bsum)
{
    __shared__ int sh[1024];
    int tid = threadIdx.x;
    int v = (tid < NB_SCAN) ? bsum[tid] : 0;
    sh[tid] = v;
    __syncthreads();
    #pragma unroll
    for (int d = 1; d < 1024; d <<= 1) {
        int t = (tid >= d) ? sh[tid - d] : 0;
        __syncthreads();
        sh[tid] += t;
        __syncthreads();
    }
    if (tid < NB_SCAN) bsum[tid] = sh[tid] - v;
    if (tid == 1023) bsum[NB_SCAN] = sh[1023];
}

__global__ __launch_bounds__(256) void add_offsets(
    int* __restrict__ off, const int* __restrict__ bsum, int n)
{
    int i = blockIdx.x * 256 + threadIdx.x;
    if (i < n) off[i] += bsum[i >> 8];
    else if (i == n) off[n] = bsum[NB_SCAN];
}

__global__ __launch_bounds__(256) void fill_sliced(
    const int* __restrict__ edge_ui, const int* __restrict__ edge_iu,
    const int* __restrict__ off, const int2* __restrict__ rank2,
    int* __restrict__ srcbuf)
{
    const int r = blockIdx.x & 7;
    const int chunk = blockIdx.x >> 3;
    const int base = chunk * FILL_EPB + threadIdx.x;
    #pragma unroll
    for (int j = 0; j < FILL_EPB / 256; ++j) {
        int i = base + j * 256;
        if (i < NEDGE) {
            int d0 = edge_ui[NEDGE + i];
            int d1 = edge_iu[NEDGE + i] + N_ITEM;
            int2 rk = rank2[i];
            if (d0 / SLICE_DIV == r)
                srcbuf[off[d0] + rk.x] = edge_ui[i];
            if (d1 / SLICE_DIV == r)
                srcbuf[off[d1] + rk.y] = edge_iu[i];
        }
    }
}

// ---------------------------------------------------------------------------
// Column-chunked, XCD-affine gather + GIN combine. Row split into 4 chunks
// of 64B. slot = blockIdx%8: slots 0-3 = item gather, chunk=slot (XCD c owns
// user-table chunk c); slots 4-7 = user gather, chunk=slot-4. Per-XCD L2
// working set = one table chunk (6.4/3.2 MB) instead of 13MB -> neighbor
// fetch approaches the 38.4MB compulsory minimum. Wave: 16 groups x 4 lanes
// x 16B (one full 64B line per edge); reduce = 4 shuffle rounds.
// out = bf16((1+eps)*x + sum F), group 0 writes one 64B line per node-chunk.
// ---------------------------------------------------------------------------
__global__ __launch_bounds__(256) void gather_chunk(
    const bf16_t* __restrict__ xu, const bf16_t* __restrict__ xi,
    const float* __restrict__ eps2,            // eps + 2*l: [item, user]
    const int* __restrict__ off_all, const int* __restrict__ srcbuf,
    bf16_t* __restrict__ ti, bf16_t* __restrict__ tu)
{
    int b = blockIdx.x;
    int slot = b & 7, idx = b >> 3;
    bool isItem = slot < 4;
    if (isItem && idx >= 12500) return;        // items need half the idx range
    int chunk = isItem ? slot : slot - 4;
    int wave = threadIdx.x >> 6;
    int node = idx * 4 + wave;
    int M = isItem ? N_ITEM : N_USER;
    if (node >= M) return;

    const bfvec8* F = reinterpret_cast<const bfvec8*>(isItem ? xu : xi);
    const bfvec8* X = reinterpret_cast<const bfvec8*>(isItem ? xi : xu);
    const int* off = isItem ? off_all : off_all + N_ITEM;
    bfvec8* out = reinterpret_cast<bfvec8*>(isItem ? ti : tu);
    float s = 1.f + (isItem ? eps2[0] : eps2[1]);

    int lane = threadIdx.x & 63;
    int grp = lane >> 2, l4 = lane & 3;        // 16 groups x 4 lanes
    int cbase = chunk * 4 + l4;                // bfvec8 unit within row
    int start = off[node], end = off[node + 1];

    float acc[8];
    #pragma unroll
    for (int j = 0; j < 8; ++j) acc[j] = 0.f;

    for (int e = start + grp; e < end; e += 16) {
        bfvec8 v = F[(size_t)srcbuf[e] * 16 + cbase];
        #pragma unroll
        for (int j = 0; j < 8; ++j) acc[j] += (float)v[j];
    }

    // reduce across the 16 groups (lane bits 2..5)
    #pragma unroll
    for (int j = 0; j < 8; ++j) {
        acc[j] += __shfl_xor(acc[j], 4, 64);
        acc[j] += __shfl_xor(acc[j], 8, 64);
        acc[j] += __shfl_xor(acc[j], 16, 64);
        acc[j] += __shfl_xor(acc[j], 32, 64);
    }

    if (grp == 0) {
        bfvec8 xv = X[(size_t)node * 16 + cbase];
        bfvec8 o;
        #pragma unroll
        for (int j = 0; j < 8; ++j) o[j] = (bf16_t)(s * (float)xv[j] + acc[j]);
        out[(size_t)node * 16 + cbase] = o;
    }
}

// ---------------------------------------------------------------------------
// Fused MLP + LayerNorm + ReLU, both node types (R3-proven structure) with a
// SINGLE 34.8KB LDS buffer: H1 round-trips through Wt (proven R6 mlp_role).
// 512 thr (8 waves x 16 rows); input t rows are pre-combined bf16.
// launch_bounds(512,6) caps VGPR ~85 -> 3 blocks/CU (LDS allows 4).
// ---------------------------------------------------------------------------
__global__ __launch_bounds__(512, 6) void mlp_ln_both(
    const bf16_t* __restrict__ ti, const bf16_t* __restrict__ tu,
    const bf16_t* __restrict__ wg,    // this layer: [itemW1,itemW2,userW1,userW2] bf16 [n][k]
    const float* __restrict__ mlpb,   // mlp_b + l*4*128
    const float* __restrict__ lng,    // ln_g + l*2*128
    const float* __restrict__ lnb,    // ln_b + l*2*128
    bf16_t* __restrict__ xib, bf16_t* __restrict__ xub,   // bf16 outs (l=0)
    float* __restrict__ xif, float* __restrict__ xuf,     // fp32 outs (l=1)
    int f32out)
{
    __shared__ __align__(16) bf16_t Wt[128 * LDW];

    const int gBI = (N_ITEM + 127) / 128;
    int b = blockIdx.x;
    bool isItem = b < gBI;
    const bf16_t* X = isItem ? ti : tu;
    bf16_t* Yb      = isItem ? xib : xub;
    float*  Yf      = isItem ? xif : xuf;
    int M  = isItem ? N_ITEM : N_USER;
    int bx = isItem ? b : b - gBI;
    const bf16_t* W1 = wg + (isItem ? 0 : 2) * 16384;
    const bf16_t* W2 = W1 + 16384;
    const float* B1 = mlpb + (isItem ? 0 : 2) * 128;
    const float* B2 = B1 + 128;
    const float* G  = lng + (isItem ? 128 : 0);
    const float* Bb = lnb + (isItem ? 128 : 0);

    const int tid = threadIdx.x;
    stage_wbf<512>(Wt, W1, tid);
    __syncthreads();

    const int wave = tid >> 6, lane = tid & 63;
    const int quad = lane >> 4, ln16 = lane & 15;
    const int row_l = wave * 16 + ln16;
    const int rowg = bx * 128 + row_l;
    const int rowc = rowg < M ? rowg : 0;

    // ---- GEMM1 from global t ----
    bfvec8 xb[4];
    const bf16_t* xp = X + (size_t)rowc * CDIM + quad * 8;
    #pragma unroll
    for (int kc = 0; kc < 4; ++kc)
        xb[kc] = *reinterpret_cast<const bfvec8*>(xp + kc * 32);

    f32x4 acc[8];
    #pragma unroll
    for (int t = 0; t < 8; ++t) acc[t] = (f32x4){0.f, 0.f, 0.f, 0.f};
    #pragma unroll
    for (int t = 0; t < 8; ++t) {
        const bf16_t* wp = &Wt[(t * 16 + ln16) * LDW + quad * 8];
        #pragma unroll
        for (int kc = 0; kc < 4; ++kc) {
            bfvec8 wv = *reinterpret_cast<const bfvec8*>(wp + kc * 32);
            acc[t] = __builtin_amdgcn_mfma_f32_16x16x32_bf16(wv, xb[kc], acc[t], 0, 0, 0);
        }
    }
    __syncthreads();                 // all W1 reads done; Wt reusable

    // H1 (bias+ReLU) into Wt as [row][col] tile
    #pragma unroll
    for (int t = 0; t < 8; ++t) {
        f32x4 bv = *reinterpret_cast<const f32x4*>(&B1[t * 16 + quad * 4]);
        bfvec4 o;
        #pragma unroll
        for (int r = 0; r < 4; ++r) {
            float v = acc[t][r] + bv[r];
            o[r] = (bf16_t)(v > 0.f ? v : 0.f);
        }
        *reinterpret_cast<bfvec4*>(&Wt[row_l * LDW + t * 16 + quad * 4]) = o;
    }
    __syncthreads();

    bfvec8 hb[4];
    #pragma unroll
    for (int kc = 0; kc < 4; ++kc)
        hb[kc] = *reinterpret_cast<const bfvec8*>(&Wt[row_l * LDW + kc * 32 + quad * 8]);
    __syncthreads();                 // all H1 reads done

    stage_wbf<512>(Wt, W2, tid);
    __syncthreads();

    // ---- GEMM2 + bias + ReLU + LayerNorm + ReLU -> Y ----
    #pragma unroll
    for (int t = 0; t < 8; ++t) acc[t] = (f32x4){0.f, 0.f, 0.f, 0.f};
    #pragma unroll
    for (int t = 0; t < 8; ++t) {
        const bf16_t* wp = &Wt[(t * 16 + ln16) * LDW + quad * 8];
        #pragma unroll
        for (int kc = 0; kc < 4; ++kc) {
            bfvec8 wv = *reinterpret_cast<const bfvec8*>(wp + kc * 32);
            acc[t] = __builtin_amdgcn_mfma_f32_16x16x32_bf16(wv, hb[kc], acc[t], 0, 0, 0);
        }
    }

    #pragma unroll
    for (int t = 0; t < 8; ++t) {
        f32x4 bv = *reinterpret_cast<const f32x4*>(&B2[t * 16 + quad * 4]);
        #pragma unroll
        for (int r = 0; r < 4; ++r) {
            float v = acc[t][r] + bv[r];
            acc[t][r] = v > 0.f ? v : 0.f;
        }
    }

    float sm = 0.f;
    #pragma unroll
    for (int t = 0; t < 8; ++t)
        #pragma unroll
        for (int r = 0; r < 4; ++r) sm += acc[t][r];
    sm += __shfl_xor(sm, 16, 64);
    sm += __shfl_xor(sm, 32, 64);
    float mean = sm * (1.f / 128.f);
    float sq = 0.f;
    #pragma unroll
    for (int t = 0; t < 8; ++t)
        #pragma unroll
        for (int r = 0; r < 4; ++r) { float d = acc[t][r] - mean; sq += d * d; }
    sq += __shfl_xor(sq, 16, 64);
    sq += __shfl_xor(sq, 32, 64);
    float rs = rsqrtf(sq * (1.f / 128.f) + 1e-5f);

    if (rowg < M) {
        if (f32out) {
            #pragma unroll
            for (int t = 0; t < 8; ++t) {
                f32x4 g4 = *reinterpret_cast<const f32x4*>(&G[t * 16 + quad * 4]);
                f32x4 b4 = *reinterpret_cast<const f32x4*>(&Bb[t * 16 + quad * 4]);
                f32x4 y;
                #pragma unroll
                for (int r = 0; r < 4; ++r) {
                    float v = (acc[t][r] - mean) * rs * g4[r] + b4[r];
                    y[r] = v > 0.f ? v : 0.f;
                }
                *reinterpret_cast<f32x4*>(&Yf[(size_t)rowg * CDIM + t * 16 + quad * 4]) = y;
            }
        } else {
            #pragma unroll
            for (int t = 0; t < 8; ++t) {
                f32x4 g4 = *reinterpret_cast<const f32x4*>(&G[t * 16 + quad * 4]);
                f32x4 b4 = *reinterpret_cast<const f32x4*>(&Bb[t * 16 + quad * 4]);
                bfvec4 y;
                #pragma unroll
                for (int r = 0; r < 4; ++r) {
                    float v = (acc[t][r] - mean) * rs * g4[r] + b4[r];
                    y[r] = (bf16_t)(v > 0.f ? v : 0.f);
                }
                *reinterpret_cast<bfvec4*>(&Yb[(size_t)rowg * CDIM + t * 16 + quad * 4]) = y;
            }
        }
    }
}

// ---------------------------------------------------------------------------
extern "C" void kernel_launch(void* const* d_in, const int* in_sizes, int n_in,
                              void* d_out, int out_size, void* d_ws, size_t ws_size,
                              hipStream_t stream)
{
    const float* x_user = (const float*)d_in[0];
    const float* x_item = (const float*)d_in[1];
    const float* W_init = (const float*)d_in[2];
    const float* b_init = (const float*)d_in[3];
    const float* mlp_W  = (const float*)d_in[4];
    const float* mlp_b  = (const float*)d_in[5];
    const float* eps    = (const float*)d_in[6];
    const float* ln_g   = (const float*)d_in[7];
    const float* ln_b   = (const float*)d_in[8];
    const int* edge_ui  = (const int*)d_in[9];
    const int* edge_iu  = (const int*)d_in[10];

    float* xuf = (float*)d_out;                     // [N_USER,128]
    float* xif = xuf + (size_t)N_USER * CDIM;       // [N_ITEM,128]

    char* w = (char*)d_ws;
    bf16_t* xub = (bf16_t*)w;                                  // 25.6 MB
    bf16_t* xib = xub + (size_t)N_USER * CDIM;                 // 12.8 MB
    bf16_t* tub = xib + (size_t)N_ITEM * CDIM;                 // 25.6 MB
    bf16_t* tib = tub + (size_t)N_USER * CDIM;                 // 12.8 MB
    int* off_all = (int*)(tib + (size_t)N_ITEM * CDIM);        // N_SEG+1
    int* bsum    = off_all + (N_SEG + 4);
    int* srcbuf  = bsum + (NB_SCAN + 2);                       // 2*NEDGE
    bf16_t* wtg  = (bf16_t*)(srcbuf + 2 * NEDGE);              // 10*16384 bf16

    // rank2 aliases tub: live only hist_rank -> fill_sliced, before gather
    // writes tub. 4.8 MB < 25.6 MB region.
    int2* rank2 = (int2*)tub;

    const int gU = (N_USER + 127) / 128;            // 782
    const int gI = (N_ITEM + 127) / 128;            // 391
    const int gSeg = (N_SEG + 256) / 256;
    const int gE = (NEDGE + 255) / 256;             // 2344

    prep_weights<<<640, 256, 0, stream>>>(W_init, mlp_W, wtg);

    // CSR prep (proven pipeline)
    zero_i32<<<(N_SEG + 255) / 256, 256, 0, stream>>>(off_all, N_SEG);
    hist_rank<<<gE, 256, 0, stream>>>(edge_ui, edge_iu, off_all, rank2);
    block_scan<<<NB_SCAN, 256, 0, stream>>>(off_all, bsum, N_SEG);
    scan_bsums<<<1, 1024, 0, stream>>>(bsum);
    add_offsets<<<gSeg, 256, 0, stream>>>(off_all, bsum, N_SEG);
    fill_sliced<<<FILL_NCHUNK * 8, 256, 0, stream>>>(edge_ui, edge_iu, off_all, rank2, srcbuf);

    // initial projection -> bf16 ws
    gemm_init<<<gU, 512, 0, stream>>>(x_user, wtg,         b_init,       xub, N_USER);
    gemm_init<<<gI, 512, 0, stream>>>(x_item, wtg + 16384, b_init + 128, xib, N_ITEM);

    for (int l = 0; l < 2; ++l) {
        gather_chunk<<<GCH, 256, 0, stream>>>(
            xub, xib, eps + 2 * l, off_all, srcbuf, tib, tub);
        mlp_ln_both<<<gI + gU, 512, 0, stream>>>(
            tib, tub, wtg + (size_t)(2 + l * 4) * 16384, mlp_b + l * 4 * 128,
            ln_g + l * 2 * 128, ln_b + l * 2 * 128,
            xib, xub, xif, xuf, (l == 1) ? 1 : 0);
    }
}

// Round 8
// 498.063 us; speedup vs baseline: 1.7262x; 1.7262x over previous
//
#include <hip/hip_runtime.h>
#include <cstdint>
#include <cstddef>

#define N_USER 100000
#define N_ITEM 50000
#define CDIM   128
#define NEDGE  600000
#define N_SEG  (N_ITEM + N_USER)          // item segments first, then user
#define NB_SCAN ((N_SEG + 255) / 256)     // 586 scan blocks

// slice geometry: slices 0-3 items (12500 segs), 4-7 users (25000 segs)
#define EPB 2048
#define NCHUNK ((NEDGE + EPB - 1) / EPB)  // 293
#define ISL 12500
#define USL 25000

typedef __bf16 bf16_t;
typedef bf16_t bfvec8 __attribute__((ext_vector_type(8)));
typedef bf16_t bfvec4 __attribute__((ext_vector_type(4)));
typedef float  f32x4  __attribute__((ext_vector_type(4)));

#define LDW 136   // LDS row stride (elems) for 128-wide bf16 tiles

// ---------------------------------------------------------------------------
// One-time: transpose+cvt all 10 weight matrices to bf16 [n][k] in ws.
// ---------------------------------------------------------------------------
__global__ __launch_bounds__(256) void prep_weights(
    const float* __restrict__ W_init, const float* __restrict__ mlp_W,
    bf16_t* __restrict__ wtg)
{
    int m  = blockIdx.x >> 6;
    int it = blockIdx.x & 63;
    const float* src = (m < 2) ? (W_init + (size_t)m * 16384)
                               : (mlp_W + (size_t)(m - 2) * 16384);
    int e = it * 256 + threadIdx.x;      // e = n*128 + k
    int n = e >> 7, k = e & 127;
    wtg[(size_t)m * 16384 + e] = (bf16_t)src[k * 128 + n];
}

template <int NT>
static __device__ inline void stage_wbf(bf16_t* Wt, const bf16_t* __restrict__ Wg, int tid) {
    #pragma unroll
    for (int c = tid; c < 2048; c += NT) {
        int n = c >> 4, koff = (c & 15) * 8;
        *reinterpret_cast<bfvec8*>(&Wt[n * LDW + koff]) =
            *reinterpret_cast<const bfvec8*>(&Wg[n * 128 + koff]);
    }
}

// ---------------------------------------------------------------------------
// Init GEMM (proven R2): swapped MFMA operands, lane holds 4 consecutive
// output cols of its own row => vector stores. 512 thr.
// ---------------------------------------------------------------------------
__global__ __launch_bounds__(512) void gemm_init(
    const float* __restrict__ X,
    const bf16_t* __restrict__ Wg,     // pre-transposed bf16 [n][k]
    const float* __restrict__ B,
    bf16_t* __restrict__ Y, int M)
{
    __shared__ __align__(16) bf16_t Wt[128 * LDW];
    const int tid = threadIdx.x;
    stage_wbf<512>(Wt, Wg, tid);
    __syncthreads();

    const int wave = tid >> 6, lane = tid & 63;
    const int quad = lane >> 4, ln16 = lane & 15;
    const int row_l = wave * 16 + ln16;
    const int rowg = blockIdx.x * 128 + row_l;
    const int rowc = rowg < M ? rowg : 0;

    bfvec8 xb[4];
    const float* xp = X + (size_t)rowc * CDIM + quad * 8;
    #pragma unroll
    for (int kc = 0; kc < 4; ++kc) {
        f32x4 lo = *reinterpret_cast<const f32x4*>(xp + kc * 32);
        f32x4 hi = *reinterpret_cast<const f32x4*>(xp + kc * 32 + 4);
        #pragma unroll
        for (int j = 0; j < 4; ++j) {
            xb[kc][j]     = (bf16_t)lo[j];
            xb[kc][j + 4] = (bf16_t)hi[j];
        }
    }

    f32x4 acc[8];
    #pragma unroll
    for (int t = 0; t < 8; ++t) acc[t] = (f32x4){0.f, 0.f, 0.f, 0.f};
    #pragma unroll
    for (int t = 0; t < 8; ++t) {
        const bf16_t* wp = &Wt[(t * 16 + ln16) * LDW + quad * 8];
        #pragma unroll
        for (int kc = 0; kc < 4; ++kc) {
            bfvec8 wv = *reinterpret_cast<const bfvec8*>(wp + kc * 32);
            acc[t] = __builtin_amdgcn_mfma_f32_16x16x32_bf16(wv, xb[kc], acc[t], 0, 0, 0);
        }
    }

    if (rowg < M) {
        #pragma unroll
        for (int t = 0; t < 8; ++t) {
            f32x4 bv = *reinterpret_cast<const f32x4*>(&B[t * 16 + quad * 4]);
            bfvec4 o;
            #pragma unroll
            for (int r = 0; r < 4; ++r) o[r] = (bf16_t)(acc[t][r] + bv[r]);
            *reinterpret_cast<bfvec4*>(&Y[(size_t)rowg * CDIM + t * 16 + quad * 4]) = o;
        }
    }
}

// ---------------------------------------------------------------------------
// CSR build. XCD-sliced histogram: block (chunk, r) increments only deg
// entries in slice r -> each deg line is touched by ONE XCD (round-robin
// blockIdx%8), stays in its L2, written back once (vs ping-pong writeback
// per migration: 77MB observed in R6 fuse_a). Correctness is mapping-free.
// ---------------------------------------------------------------------------
__global__ __launch_bounds__(256) void zero_i32(int* __restrict__ p, int n)
{
    int i = blockIdx.x * 256 + threadIdx.x;
    if (i < n) p[i] = 0;
}

__global__ __launch_bounds__(256) void hist_sliced(
    const int* __restrict__ edge_ui, const int* __restrict__ edge_iu,
    int* __restrict__ deg)
{
    const int r = blockIdx.x & 7;
    const int base = (blockIdx.x >> 3) * EPB + threadIdx.x;
    if (r < 4) {
        const int lo = r * ISL, hi = lo + ISL;
        #pragma unroll
        for (int j = 0; j < EPB / 256; ++j) {
            int i = base + j * 256;
            if (i < NEDGE) {
                int d = edge_ui[NEDGE + i];
                if (d >= lo && d < hi) atomicAdd(&deg[d], 1);
            }
        }
    } else {
        const int lo = (r - 4) * USL, hi = lo + USL;
        #pragma unroll
        for (int j = 0; j < EPB / 256; ++j) {
            int i = base + j * 256;
            if (i < NEDGE) {
                int d = edge_iu[NEDGE + i];
                if (d >= lo && d < hi) atomicAdd(&deg[N_ITEM + d], 1);
            }
        }
    }
}

__global__ __launch_bounds__(256) void block_scan(
    int* __restrict__ off, int* __restrict__ bsum, int n)
{
    __shared__ int sh[256];
    int tid = threadIdx.x;
    int i = blockIdx.x * 256 + tid;
    int v = (i < n) ? off[i] : 0;
    sh[tid] = v;
    __syncthreads();
    #pragma unroll
    for (int d = 1; d < 256; d <<= 1) {
        int t = (tid >= d) ? sh[tid - d] : 0;
        __syncthreads();
        sh[tid] += t;
        __syncthreads();
    }
    if (i < n) off[i] = sh[tid] - v;
    if (tid == 255) bsum[blockIdx.x] = sh[255];
}

__global__ __launch_bounds__(1024) void scan_bsums(int* __restrict__ bsum)
{
    __shared__ int sh[1024];
    int tid = threadIdx.x;
    int v = (tid < NB_SCAN) ? bsum[tid] : 0;
    sh[tid] = v;
    __syncthreads();
    #pragma unroll
    for (int d = 1; d < 1024; d <<= 1) {
        int t = (tid >= d) ? sh[tid - d] : 0;
        __syncthreads();
        sh[tid] += t;
        __syncthreads();
    }
    if (tid < NB_SCAN) bsum[tid] = sh[tid] - v;
    if (tid == 1023) bsum[NB_SCAN] = sh[1023];
}

__global__ __launch_bounds__(256) void add_offsets(
    int* __restrict__ off, const int* __restrict__ bsum,
    int* __restrict__ cursor, int n)
{
    int i = blockIdx.x * 256 + threadIdx.x;
    if (i < n) {
        int o = off[i] + bsum[i >> 8];
        off[i] = o;
        cursor[i] = o;
    } else if (i == n) {
        off[n] = bsum[NB_SCAN];
    }
}

// Sliced fill with XCD-local cursor atomics (R1's srcbuf slicing + localized
// RMW). slot = atomicAdd(cursor[seg]); cursor and srcbuf lines are slice-
// local -> single-XCD writers -> L2 write-combine.
__global__ __launch_bounds__(256) void fill_csr(
    const int* __restrict__ edge_ui, const int* __restrict__ edge_iu,
    int* __restrict__ cursor, int* __restrict__ srcbuf)
{
    const int r = blockIdx.x & 7;
    const int base = (blockIdx.x >> 3) * EPB + threadIdx.x;
    if (r < 4) {
        const int lo = r * ISL, hi = lo + ISL;
        #pragma unroll
        for (int j = 0; j < EPB / 256; ++j) {
            int i = base + j * 256;
            if (i < NEDGE) {
                int d = edge_ui[NEDGE + i];
                if (d >= lo && d < hi) {
                    int slot = atomicAdd(&cursor[d], 1);
                    srcbuf[slot] = edge_ui[i];
                }
            }
        }
    } else {
        const int lo = (r - 4) * USL, hi = lo + USL;
        #pragma unroll
        for (int j = 0; j < EPB / 256; ++j) {
            int i = base + j * 256;
            if (i < NEDGE) {
                int d = edge_iu[NEDGE + i];
                if (d >= lo && d < hi) {
                    int slot = atomicAdd(&cursor[N_ITEM + d], 1);
                    srcbuf[slot] = edge_iu[i];
                }
            }
        }
    }
}

// ---------------------------------------------------------------------------
// Gather + GIN combine (proven R3, 68us floor): one node per wave, 4 groups
// x 16 lanes x bfvec8 (full 256B row per load instruction group).
// out = bf16((1+eps)*x + sum F).
// ---------------------------------------------------------------------------
__global__ __launch_bounds__(256) void gather_both(
    const bf16_t* __restrict__ xu, const bf16_t* __restrict__ xi,
    const float* __restrict__ eps2,            // eps + 2*l: [item, user]
    const int* __restrict__ off_all, const int* __restrict__ srcbuf,
    bf16_t* __restrict__ ti, bf16_t* __restrict__ tu)
{
    const int gBI = (N_ITEM + 3) / 4;
    int b = blockIdx.x;
    bool isItem = b < gBI;
    int wave = threadIdx.x >> 6;
    int node = (isItem ? b : b - gBI) * 4 + wave;
    int n = isItem ? N_ITEM : N_USER;
    if (node >= n) return;

    const bfvec8* F = reinterpret_cast<const bfvec8*>(isItem ? xu : xi);
    const bfvec8* X = reinterpret_cast<const bfvec8*>(isItem ? xi : xu);
    const int* off = isItem ? off_all : off_all + N_ITEM;
    bfvec8* out = reinterpret_cast<bfvec8*>(isItem ? ti : tu);
    float s = 1.f + (isItem ? eps2[0] : eps2[1]);

    int lane = threadIdx.x & 63;
    int grp  = lane >> 4;        // 0..3: edge phase
    int l16  = lane & 15;        // 16B chunk within row
    int start = off[node], end = off[node + 1];

    float acc[8];
    #pragma unroll
    for (int j = 0; j < 8; ++j) acc[j] = 0.f;

    int e = start + grp;
    for (; e + 12 < end; e += 16) {
        int s0 = srcbuf[e];
        int s1 = srcbuf[e + 4];
        int s2 = srcbuf[e + 8];
        int s3 = srcbuf[e + 12];
        bfvec8 v0 = F[(size_t)s0 * 16 + l16];
        bfvec8 v1 = F[(size_t)s1 * 16 + l16];
        bfvec8 v2 = F[(size_t)s2 * 16 + l16];
        bfvec8 v3 = F[(size_t)s3 * 16 + l16];
        #pragma unroll
        for (int j = 0; j < 8; ++j)
            acc[j] += ((float)v0[j] + (float)v1[j]) + ((float)v2[j] + (float)v3[j]);
    }
    for (; e + 4 < end; e += 8) {
        int s0 = srcbuf[e];
        int s1 = srcbuf[e + 4];
        bfvec8 v0 = F[(size_t)s0 * 16 + l16];
        bfvec8 v1 = F[(size_t)s1 * 16 + l16];
        #pragma unroll
        for (int j = 0; j < 8; ++j) acc[j] += (float)v0[j] + (float)v1[j];
    }
    for (; e < end; e += 4) {
        bfvec8 v = F[(size_t)srcbuf[e] * 16 + l16];
        #pragma unroll
        for (int j = 0; j < 8; ++j) acc[j] += (float)v[j];
    }

    #pragma unroll
    for (int j = 0; j < 8; ++j) {
        acc[j] += __shfl_xor(acc[j], 16, 64);
        acc[j] += __shfl_xor(acc[j], 32, 64);
    }

    if (grp == 0) {
        bfvec8 xv = X[(size_t)node * 16 + l16];
        bfvec8 o;
        #pragma unroll
        for (int j = 0; j < 8; ++j) o[j] = (bf16_t)(s * (float)xv[j] + acc[j]);
        out[(size_t)node * 16 + l16] = o;
    }
}

// ---------------------------------------------------------------------------
// Fused MLP + LayerNorm + ReLU, both node types. SINGLE 34.8KB LDS buffer
// (H1 round-trips through Wt — verified R7): 3 blocks/CU vs 2.
// 512 thr (8 waves x 16 rows), weights pre-transposed bf16.
// ---------------------------------------------------------------------------
__global__ __launch_bounds__(512, 6) void mlp_ln_both(
    const bf16_t* __restrict__ ti, const bf16_t* __restrict__ tu,
    const bf16_t* __restrict__ wg,    // this layer: [itemW1,itemW2,userW1,userW2] bf16 [n][k]
    const float* __restrict__ mlpb,   // mlp_b + l*4*128
    const float* __restrict__ lng,    // ln_g + l*2*128
    const float* __restrict__ lnb,    // ln_b + l*2*128
    bf16_t* __restrict__ xib, bf16_t* __restrict__ xub,   // bf16 outs (l=0)
    float* __restrict__ xif, float* __restrict__ xuf,     // fp32 outs (l=1)
    int f32out)
{
    __shared__ __align__(16) bf16_t Wt[128 * LDW];

    const int gBI = (N_ITEM + 127) / 128;
    int b = blockIdx.x;
    bool isItem = b < gBI;
    const bf16_t* X = isItem ? ti : tu;
    bf16_t* Yb      = isItem ? xib : xub;
    float*  Yf      = isItem ? xif : xuf;
    int M  = isItem ? N_ITEM : N_USER;
    int bx = isItem ? b : b - gBI;
    const bf16_t* W1 = wg + (isItem ? 0 : 2) * 16384;
    const bf16_t* W2 = W1 + 16384;
    const float* B1 = mlpb + (isItem ? 0 : 2) * 128;
    const float* B2 = B1 + 128;
    const float* G  = lng + (isItem ? 128 : 0);
    const float* Bb = lnb + (isItem ? 128 : 0);

    const int tid = threadIdx.x;
    stage_wbf<512>(Wt, W1, tid);
    __syncthreads();

    const int wave = tid >> 6, lane = tid & 63;
    const int quad = lane >> 4, ln16 = lane & 15;
    const int row_l = wave * 16 + ln16;
    const int rowg = bx * 128 + row_l;
    const int rowc = rowg < M ? rowg : 0;

    // ---- GEMM1 from global t ----
    bfvec8 xb[4];
    const bf16_t* xp = X + (size_t)rowc * CDIM + quad * 8;
    #pragma unroll
    for (int kc = 0; kc < 4; ++kc)
        xb[kc] = *reinterpret_cast<const bfvec8*>(xp + kc * 32);

    f32x4 acc[8];
    #pragma unroll
    for (int t = 0; t < 8; ++t) acc[t] = (f32x4){0.f, 0.f, 0.f, 0.f};
    #pragma unroll
    for (int t = 0; t < 8; ++t) {
        const bf16_t* wp = &Wt[(t * 16 + ln16) * LDW + quad * 8];
        #pragma unroll
        for (int kc = 0; kc < 4; ++kc) {
            bfvec8 wv = *reinterpret_cast<const bfvec8*>(wp + kc * 32);
            acc[t] = __builtin_amdgcn_mfma_f32_16x16x32_bf16(wv, xb[kc], acc[t], 0, 0, 0);
        }
    }
    __syncthreads();                 // all W1 reads done; Wt reusable

    // H1 (bias+ReLU) into Wt as [row][col] tile
    #pragma unroll
    for (int t = 0; t < 8; ++t) {
        f32x4 bv = *reinterpret_cast<const f32x4*>(&B1[t * 16 + quad * 4]);
        bfvec4 o;
        #pragma unroll
        for (int r = 0; r < 4; ++r) {
            float v = acc[t][r] + bv[r];
            o[r] = (bf16_t)(v > 0.f ? v : 0.f);
        }
        *reinterpret_cast<bfvec4*>(&Wt[row_l * LDW + t * 16 + quad * 4]) = o;
    }
    __syncthreads();

    bfvec8 hb[4];
    #pragma unroll
    for (int kc = 0; kc < 4; ++kc)
        hb[kc] = *reinterpret_cast<const bfvec8*>(&Wt[row_l * LDW + kc * 32 + quad * 8]);
    __syncthreads();                 // all H1 reads done

    stage_wbf<512>(Wt, W2, tid);
    __syncthreads();

    // ---- GEMM2 + bias + ReLU + LayerNorm + ReLU -> Y ----
    #pragma unroll
    for (int t = 0; t < 8; ++t) acc[t] = (f32x4){0.f, 0.f, 0.f, 0.f};
    #pragma unroll
    for (int t = 0; t < 8; ++t) {
        const bf16_t* wp = &Wt[(t * 16 + ln16) * LDW + quad * 8];
        #pragma unroll
        for (int kc = 0; kc < 4; ++kc) {
            bfvec8 wv = *reinterpret_cast<const bfvec8*>(wp + kc * 32);
            acc[t] = __builtin_amdgcn_mfma_f32_16x16x32_bf16(wv, hb[kc], acc[t], 0, 0, 0);
        }
    }

    #pragma unroll
    for (int t = 0; t < 8; ++t) {
        f32x4 bv = *reinterpret_cast<const f32x4*>(&B2[t * 16 + quad * 4]);
        #pragma unroll
        for (int r = 0; r < 4; ++r) {
            float v = acc[t][r] + bv[r];
            acc[t][r] = v > 0.f ? v : 0.f;
        }
    }

    float sm = 0.f;
    #pragma unroll
    for (int t = 0; t < 8; ++t)
        #pragma unroll
        for (int r = 0; r < 4; ++r) sm += acc[t][r];
    sm += __shfl_xor(sm, 16, 64);
    sm += __shfl_xor(sm, 32, 64);
    float mean = sm * (1.f / 128.f);
    float sq = 0.f;
    #pragma unroll
    for (int t = 0; t < 8; ++t)
        #pragma unroll
        for (int r = 0; r < 4; ++r) { float d = acc[t][r] - mean; sq += d * d; }
    sq += __shfl_xor(sq, 16, 64);
    sq += __shfl_xor(sq, 32, 64);
    float rs = rsqrtf(sq * (1.f / 128.f) + 1e-5f);

    if (rowg < M) {
        if (f32out) {
            #pragma unroll
            for (int t = 0; t < 8; ++t) {
                f32x4 g4 = *reinterpret_cast<const f32x4*>(&G[t * 16 + quad * 4]);
                f32x4 b4 = *reinterpret_cast<const f32x4*>(&Bb[t * 16 + quad * 4]);
                f32x4 y;
                #pragma unroll
                for (int r = 0; r < 4; ++r) {
                    float v = (acc[t][r] - mean) * rs * g4[r] + b4[r];
                    y[r] = v > 0.f ? v : 0.f;
                }
                *reinterpret_cast<f32x4*>(&Yf[(size_t)rowg * CDIM + t * 16 + quad * 4]) = y;
            }
        } else {
            #pragma unroll
            for (int t = 0; t < 8; ++t) {
                f32x4 g4 = *reinterpret_cast<const f32x4*>(&G[t * 16 + quad * 4]);
                f32x4 b4 = *reinterpret_cast<const f32x4*>(&Bb[t * 16 + quad * 4]);
                bfvec4 y;
                #pragma unroll
                for (int r = 0; r < 4; ++r) {
                    float v = (acc[t][r] - mean) * rs * g4[r] + b4[r];
                    y[r] = (bf16_t)(v > 0.f ? v : 0.f);
                }
                *reinterpret_cast<bfvec4*>(&Yb[(size_t)rowg * CDIM + t * 16 + quad * 4]) = y;
            }
        }
    }
}

// ---------------------------------------------------------------------------
extern "C" void kernel_launch(void* const* d_in, const int* in_sizes, int n_in,
                              void* d_out, int out_size, void* d_ws, size_t ws_size,
                              hipStream_t stream)
{
    const float* x_user = (const float*)d_in[0];
    const float* x_item = (const float*)d_in[1];
    const float* W_init = (const float*)d_in[2];
    const float* b_init = (const float*)d_in[3];
    const float* mlp_W  = (const float*)d_in[4];
    const float* mlp_b  = (const float*)d_in[5];
    const float* eps    = (const float*)d_in[6];
    const float* ln_g   = (const float*)d_in[7];
    const float* ln_b   = (const float*)d_in[8];
    const int* edge_ui  = (const int*)d_in[9];
    const int* edge_iu  = (const int*)d_in[10];

    float* xuf = (float*)d_out;                     // [N_USER,128]
    float* xif = xuf + (size_t)N_USER * CDIM;       // [N_ITEM,128]

    char* w = (char*)d_ws;
    bf16_t* xub = (bf16_t*)w;                                  // 25.6 MB
    bf16_t* xib = xub + (size_t)N_USER * CDIM;                 // 12.8 MB
    bf16_t* tub = xib + (size_t)N_ITEM * CDIM;                 // 25.6 MB
    bf16_t* tib = tub + (size_t)N_USER * CDIM;                 // 12.8 MB
    int* off_all = (int*)(tib + (size_t)N_ITEM * CDIM);        // N_SEG+1
    int* cursor  = off_all + (N_SEG + 4);                      // N_SEG
    int* bsum    = cursor + N_SEG;
    int* srcbuf  = bsum + (NB_SCAN + 2);                       // 2*NEDGE
    bf16_t* wtg  = (bf16_t*)(srcbuf + 2 * NEDGE);              // 10*16384 bf16

    const int gU = (N_USER + 127) / 128;            // 782
    const int gI = (N_ITEM + 127) / 128;            // 391
    const int gSeg = (N_SEG + 256) / 256;
    const int gGather = (N_ITEM + 3) / 4 + (N_USER + 3) / 4;

    prep_weights<<<640, 256, 0, stream>>>(W_init, mlp_W, wtg);

    // CSR prep: sliced hist (XCD-local atomics) -> scan -> sliced cursor fill
    zero_i32<<<(N_SEG + 255) / 256, 256, 0, stream>>>(off_all, N_SEG);
    hist_sliced<<<NCHUNK * 8, 256, 0, stream>>>(edge_ui, edge_iu, off_all);
    block_scan<<<NB_SCAN, 256, 0, stream>>>(off_all, bsum, N_SEG);
    scan_bsums<<<1, 1024, 0, stream>>>(bsum);
    add_offsets<<<gSeg, 256, 0, stream>>>(off_all, bsum, cursor, N_SEG);
    fill_csr<<<NCHUNK * 8, 256, 0, stream>>>(edge_ui, edge_iu, cursor, srcbuf);

    // initial projection -> bf16 ws
    gemm_init<<<gU, 512, 0, stream>>>(x_user, wtg,         b_init,       xub, N_USER);
    gemm_init<<<gI, 512, 0, stream>>>(x_item, wtg + 16384, b_init + 128, xib, N_ITEM);

    for (int l = 0; l < 2; ++l) {
        gather_both<<<gGather, 256, 0, stream>>>(
            xub, xib, eps + 2 * l, off_all, srcbuf, tib, tub);
        mlp_ln_both<<<gI + gU, 512, 0, stream>>>(
            tib, tub, wtg + (size_t)(2 + l * 4) * 16384, mlp_b + l * 4 * 128,
            ln_g + l * 2 * 128, ln_b + l * 2 * 128,
            xib, xub, xif, xuf, (l == 1) ? 1 : 0);
    }
}

// Round 9
// 472.319 us; speedup vs baseline: 1.8203x; 1.0545x over previous
//
#include <hip/hip_runtime.h>
#include <cstdint>
#include <cstddef>

#define N_USER 100000
#define N_ITEM 50000
#define CDIM   128
#define NEDGE  600000
#define N_SEG  (N_ITEM + N_USER)          // item segments first, then user
#define NB_SCAN ((N_SEG + 255) / 256)     // 586 scan blocks

// XCD-sliced fill parameters (proven R1)
#define FILL_EPB 2048
#define FILL_NCHUNK ((NEDGE + FILL_EPB - 1) / FILL_EPB)   // 293
#define SLICE_DIV ((N_SEG + 7) / 8)

typedef __bf16 bf16_t;
typedef bf16_t bfvec8 __attribute__((ext_vector_type(8)));
typedef bf16_t bfvec4 __attribute__((ext_vector_type(4)));
typedef float  f32x4  __attribute__((ext_vector_type(4)));

#define LDW 136   // LDS row stride (elems) for 128-wide bf16 tiles

// ---------------------------------------------------------------------------
// One-time: transpose+cvt all 10 weight matrices to bf16 [n][k] in ws.
// ---------------------------------------------------------------------------
__global__ __launch_bounds__(256) void prep_weights(
    const float* __restrict__ W_init, const float* __restrict__ mlp_W,
    bf16_t* __restrict__ wtg)
{
    int m  = blockIdx.x >> 6;
    int it = blockIdx.x & 63;
    const float* src = (m < 2) ? (W_init + (size_t)m * 16384)
                               : (mlp_W + (size_t)(m - 2) * 16384);
    int e = it * 256 + threadIdx.x;      // e = n*128 + k
    int n = e >> 7, k = e & 127;
    wtg[(size_t)m * 16384 + e] = (bf16_t)src[k * 128 + n];
}

template <int NT>
static __device__ inline void stage_wbf(bf16_t* Wt, const bf16_t* __restrict__ Wg, int tid) {
    #pragma unroll
    for (int c = tid; c < 2048; c += NT) {
        int n = c >> 4, koff = (c & 15) * 8;
        *reinterpret_cast<bfvec8*>(&Wt[n * LDW + koff]) =
            *reinterpret_cast<const bfvec8*>(&Wg[n * 128 + koff]);
    }
}

// ---------------------------------------------------------------------------
// Init GEMM (proven R2): swapped MFMA operands, lane holds 4 consecutive
// output cols of its own row => vector stores. 512 thr.
// ---------------------------------------------------------------------------
__global__ __launch_bounds__(512) void gemm_init(
    const float* __restrict__ X,
    const bf16_t* __restrict__ Wg,     // pre-transposed bf16 [n][k]
    const float* __restrict__ B,
    bf16_t* __restrict__ Y, int M)
{
    __shared__ __align__(16) bf16_t Wt[128 * LDW];
    const int tid = threadIdx.x;
    stage_wbf<512>(Wt, Wg, tid);
    __syncthreads();

    const int wave = tid >> 6, lane = tid & 63;
    const int quad = lane >> 4, ln16 = lane & 15;
    const int row_l = wave * 16 + ln16;
    const int rowg = blockIdx.x * 128 + row_l;
    const int rowc = rowg < M ? rowg : 0;

    bfvec8 xb[4];
    const float* xp = X + (size_t)rowc * CDIM + quad * 8;
    #pragma unroll
    for (int kc = 0; kc < 4; ++kc) {
        f32x4 lo = *reinterpret_cast<const f32x4*>(xp + kc * 32);
        f32x4 hi = *reinterpret_cast<const f32x4*>(xp + kc * 32 + 4);
        #pragma unroll
        for (int j = 0; j < 4; ++j) {
            xb[kc][j]     = (bf16_t)lo[j];
            xb[kc][j + 4] = (bf16_t)hi[j];
        }
    }

    f32x4 acc[8];
    #pragma unroll
    for (int t = 0; t < 8; ++t) acc[t] = (f32x4){0.f, 0.f, 0.f, 0.f};
    #pragma unroll
    for (int t = 0; t < 8; ++t) {
        const bf16_t* wp = &Wt[(t * 16 + ln16) * LDW + quad * 8];
        #pragma unroll
        for (int kc = 0; kc < 4; ++kc) {
            bfvec8 wv = *reinterpret_cast<const bfvec8*>(wp + kc * 32);
            acc[t] = __builtin_amdgcn_mfma_f32_16x16x32_bf16(wv, xb[kc], acc[t], 0, 0, 0);
        }
    }

    if (rowg < M) {
        #pragma unroll
        for (int t = 0; t < 8; ++t) {
            f32x4 bv = *reinterpret_cast<const f32x4*>(&B[t * 16 + quad * 4]);
            bfvec4 o;
            #pragma unroll
            for (int r = 0; r < 4; ++r) o[r] = (bf16_t)(acc[t][r] + bv[r]);
            *reinterpret_cast<bfvec4*>(&Y[(size_t)rowg * CDIM + t * 16 + quad * 4]) = o;
        }
    }
}

// ---------------------------------------------------------------------------
// CSR build pieces (proven R1/R3)
// ---------------------------------------------------------------------------
__global__ __launch_bounds__(256) void zero_i32(int* __restrict__ p, int n)
{
    int i = blockIdx.x * 256 + threadIdx.x;
    if (i < n) p[i] = 0;
}

// Histogram + rank capture: atomicAdd's return value IS this edge's rank
// within its destination segment. One coalesced 8B store per edge pair.
__global__ __launch_bounds__(256) void hist_rank(
    const int* __restrict__ edge_ui, const int* __restrict__ edge_iu,
    int* __restrict__ deg, int2* __restrict__ rank2)
{
    int i = blockIdx.x * 256 + threadIdx.x;
    if (i >= NEDGE) return;
    int r0 = atomicAdd(&deg[edge_ui[NEDGE + i]], 1);
    int r1 = atomicAdd(&deg[N_ITEM + edge_iu[NEDGE + i]], 1);
    rank2[i] = make_int2(r0, r1);
}

__global__ __launch_bounds__(256) void block_scan(
    int* __restrict__ off, int* __restrict__ bsum, int n)
{
    __shared__ int sh[256];
    int tid = threadIdx.x;
    int i = blockIdx.x * 256 + tid;
    int v = (i < n) ? off[i] : 0;
    sh[tid] = v;
    __syncthreads();
    #pragma unroll
    for (int d = 1; d < 256; d <<= 1) {
        int t = (tid >= d) ? sh[tid - d] : 0;
        __syncthreads();
        sh[tid] += t;
        __syncthreads();
    }
    if (i < n) off[i] = sh[tid] - v;
    if (tid == 255) bsum[blockIdx.x] = sh[255];
}

__global__ __launch_bounds__(1024) void scan_bsums(int* __restrict__ bsum)
{
    __shared__ int sh[1024];
    int tid = threadIdx.x;
    int v = (tid < NB_SCAN) ? bsum[tid] : 0;
    sh[tid] = v;
    __syncthreads();
    #pragma unroll
    for (int d = 1; d < 1024; d <<= 1) {
        int t = (tid >= d) ? sh[tid - d] : 0;
        __syncthreads();
        sh[tid] += t;
        __syncthreads();
    }
    if (tid < NB_SCAN) bsum[tid] = sh[tid] - v;
    if (tid == 1023) bsum[NB_SCAN] = sh[1023];
}

__global__ __launch_bounds__(256) void add_offsets(
    int* __restrict__ off, const int* __restrict__ bsum, int n)
{
    int i = blockIdx.x * 256 + threadIdx.x;
    if (i < n) off[i] += bsum[i >> 8];
    else if (i == n) off[n] = bsum[NB_SCAN];
}

// Atomic-free, XCD-sliced CSR fill (proven R1): slot = off[seg] + rank.
__global__ __launch_bounds__(256) void fill_sliced(
    const int* __restrict__ edge_ui, const int* __restrict__ edge_iu,
    const int* __restrict__ off, const int2* __restrict__ rank2,
    int* __restrict__ srcbuf)
{
    const int r = blockIdx.x & 7;
    const int chunk = blockIdx.x >> 3;
    const int base = chunk * FILL_EPB + threadIdx.x;
    #pragma unroll
    for (int j = 0; j < FILL_EPB / 256; ++j) {
        int i = base + j * 256;
        if (i < NEDGE) {
            int d0 = edge_ui[NEDGE + i];
            int d1 = edge_iu[NEDGE + i] + N_ITEM;
            int2 rk = rank2[i];
            if (d0 / SLICE_DIV == r)
                srcbuf[off[d0] + rk.x] = edge_ui[i];
            if (d1 / SLICE_DIV == r)
                srcbuf[off[d1] + rk.y] = edge_iu[i];
        }
    }
}

// ---------------------------------------------------------------------------
// Gather + GIN combine (proven R3, ~68us floor): one node per wave, 4 groups
// x 16 lanes x bfvec8. out = bf16((1+eps)*x + sum F).
// ---------------------------------------------------------------------------
__global__ __launch_bounds__(256) void gather_both(
    const bf16_t* __restrict__ xu, const bf16_t* __restrict__ xi,
    const float* __restrict__ eps2,            // eps + 2*l: [item, user]
    const int* __restrict__ off_all, const int* __restrict__ srcbuf,
    bf16_t* __restrict__ ti, bf16_t* __restrict__ tu)
{
    const int gBI = (N_ITEM + 3) / 4;
    int b = blockIdx.x;
    bool isItem = b < gBI;
    int wave = threadIdx.x >> 6;
    int node = (isItem ? b : b - gBI) * 4 + wave;
    int n = isItem ? N_ITEM : N_USER;
    if (node >= n) return;

    const bfvec8* F = reinterpret_cast<const bfvec8*>(isItem ? xu : xi);
    const bfvec8* X = reinterpret_cast<const bfvec8*>(isItem ? xi : xu);
    const int* off = isItem ? off_all : off_all + N_ITEM;
    bfvec8* out = reinterpret_cast<bfvec8*>(isItem ? ti : tu);
    float s = 1.f + (isItem ? eps2[0] : eps2[1]);

    int lane = threadIdx.x & 63;
    int grp  = lane >> 4;        // 0..3: edge phase
    int l16  = lane & 15;        // 16B chunk within row
    int start = off[node], end = off[node + 1];

    float acc[8];
    #pragma unroll
    for (int j = 0; j < 8; ++j) acc[j] = 0.f;

    int e = start + grp;
    for (; e + 12 < end; e += 16) {
        int s0 = srcbuf[e];
        int s1 = srcbuf[e + 4];
        int s2 = srcbuf[e + 8];
        int s3 = srcbuf[e + 12];
        bfvec8 v0 = F[(size_t)s0 * 16 + l16];
        bfvec8 v1 = F[(size_t)s1 * 16 + l16];
        bfvec8 v2 = F[(size_t)s2 * 16 + l16];
        bfvec8 v3 = F[(size_t)s3 * 16 + l16];
        #pragma unroll
        for (int j = 0; j < 8; ++j)
            acc[j] += ((float)v0[j] + (float)v1[j]) + ((float)v2[j] + (float)v3[j]);
    }
    for (; e + 4 < end; e += 8) {
        int s0 = srcbuf[e];
        int s1 = srcbuf[e + 4];
        bfvec8 v0 = F[(size_t)s0 * 16 + l16];
        bfvec8 v1 = F[(size_t)s1 * 16 + l16];
        #pragma unroll
        for (int j = 0; j < 8; ++j) acc[j] += (float)v0[j] + (float)v1[j];
    }
    for (; e < end; e += 4) {
        bfvec8 v = F[(size_t)srcbuf[e] * 16 + l16];
        #pragma unroll
        for (int j = 0; j < 8; ++j) acc[j] += (float)v[j];
    }

    #pragma unroll
    for (int j = 0; j < 8; ++j) {
        acc[j] += __shfl_xor(acc[j], 16, 64);
        acc[j] += __shfl_xor(acc[j], 32, 64);
    }

    if (grp == 0) {
        bfvec8 xv = X[(size_t)node * 16 + l16];
        bfvec8 o;
        #pragma unroll
        for (int j = 0; j < 8; ++j) o[j] = (bf16_t)(s * (float)xv[j] + acc[j]);
        out[(size_t)node * 16 + l16] = o;
    }
}

// ---------------------------------------------------------------------------
// Fused MLP + LayerNorm + ReLU, both node types. SINGLE 34.8KB LDS buffer
// (H1 round-trips through Wt — verified bit-identical R7/R8): 3 blocks/CU.
// 512 thr (8 waves x 16 rows), weights pre-transposed bf16.
// ---------------------------------------------------------------------------
__global__ __launch_bounds__(512, 6) void mlp_ln_both(
    const bf16_t* __restrict__ ti, const bf16_t* __restrict__ tu,
    const bf16_t* __restrict__ wg,    // this layer: [itemW1,itemW2,userW1,userW2] bf16 [n][k]
    const float* __restrict__ mlpb,   // mlp_b + l*4*128
    const float* __restrict__ lng,    // ln_g + l*2*128
    const float* __restrict__ lnb,    // ln_b + l*2*128
    bf16_t* __restrict__ xib, bf16_t* __restrict__ xub,   // bf16 outs (l=0)
    float* __restrict__ xif, float* __restrict__ xuf,     // fp32 outs (l=1)
    int f32out)
{
    __shared__ __align__(16) bf16_t Wt[128 * LDW];

    const int gBI = (N_ITEM + 127) / 128;
    int b = blockIdx.x;
    bool isItem = b < gBI;
    const bf16_t* X = isItem ? ti : tu;
    bf16_t* Yb      = isItem ? xib : xub;
    float*  Yf      = isItem ? xif : xuf;
    int M  = isItem ? N_ITEM : N_USER;
    int bx = isItem ? b : b - gBI;
    const bf16_t* W1 = wg + (isItem ? 0 : 2) * 16384;
    const bf16_t* W2 = W1 + 16384;
    const float* B1 = mlpb + (isItem ? 0 : 2) * 128;
    const float* B2 = B1 + 128;
    const float* G  = lng + (isItem ? 128 : 0);
    const float* Bb = lnb + (isItem ? 128 : 0);

    const int tid = threadIdx.x;
    stage_wbf<512>(Wt, W1, tid);
    __syncthreads();

    const int wave = tid >> 6, lane = tid & 63;
    const int quad = lane >> 4, ln16 = lane & 15;
    const int row_l = wave * 16 + ln16;
    const int rowg = bx * 128 + row_l;
    const int rowc = rowg < M ? rowg : 0;

    // ---- GEMM1 from global t ----
    bfvec8 xb[4];
    const bf16_t* xp = X + (size_t)rowc * CDIM + quad * 8;
    #pragma unroll
    for (int kc = 0; kc < 4; ++kc)
        xb[kc] = *reinterpret_cast<const bfvec8*>(xp + kc * 32);

    f32x4 acc[8];
    #pragma unroll
    for (int t = 0; t < 8; ++t) acc[t] = (f32x4){0.f, 0.f, 0.f, 0.f};
    #pragma unroll
    for (int t = 0; t < 8; ++t) {
        const bf16_t* wp = &Wt[(t * 16 + ln16) * LDW + quad * 8];
        #pragma unroll
        for (int kc = 0; kc < 4; ++kc) {
            bfvec8 wv = *reinterpret_cast<const bfvec8*>(wp + kc * 32);
            acc[t] = __builtin_amdgcn_mfma_f32_16x16x32_bf16(wv, xb[kc], acc[t], 0, 0, 0);
        }
    }
    __syncthreads();                 // all W1 reads done; Wt reusable

    // H1 (bias+ReLU) into Wt as [row][col] tile
    #pragma unroll
    for (int t = 0; t < 8; ++t) {
        f32x4 bv = *reinterpret_cast<const f32x4*>(&B1[t * 16 + quad * 4]);
        bfvec4 o;
        #pragma unroll
        for (int r = 0; r < 4; ++r) {
            float v = acc[t][r] + bv[r];
            o[r] = (bf16_t)(v > 0.f ? v : 0.f);
        }
        *reinterpret_cast<bfvec4*>(&Wt[row_l * LDW + t * 16 + quad * 4]) = o;
    }
    __syncthreads();

    bfvec8 hb[4];
    #pragma unroll
    for (int kc = 0; kc < 4; ++kc)
        hb[kc] = *reinterpret_cast<const bfvec8*>(&Wt[row_l * LDW + kc * 32 + quad * 8]);
    __syncthreads();                 // all H1 reads done

    stage_wbf<512>(Wt, W2, tid);
    __syncthreads();

    // ---- GEMM2 + bias + ReLU + LayerNorm + ReLU -> Y ----
    #pragma unroll
    for (int t = 0; t < 8; ++t) acc[t] = (f32x4){0.f, 0.f, 0.f, 0.f};
    #pragma unroll
    for (int t = 0; t < 8; ++t) {
        const bf16_t* wp = &Wt[(t * 16 + ln16) * LDW + quad * 8];
        #pragma unroll
        for (int kc = 0; kc < 4; ++kc) {
            bfvec8 wv = *reinterpret_cast<const bfvec8*>(wp + kc * 32);
            acc[t] = __builtin_amdgcn_mfma_f32_16x16x32_bf16(wv, hb[kc], acc[t], 0, 0, 0);
        }
    }

    #pragma unroll
    for (int t = 0; t < 8; ++t) {
        f32x4 bv = *reinterpret_cast<const f32x4*>(&B2[t * 16 + quad * 4]);
        #pragma unroll
        for (int r = 0; r < 4; ++r) {
            float v = acc[t][r] + bv[r];
            acc[t][r] = v > 0.f ? v : 0.f;
        }
    }

    float sm = 0.f;
    #pragma unroll
    for (int t = 0; t < 8; ++t)
        #pragma unroll
        for (int r = 0; r < 4; ++r) sm += acc[t][r];
    sm += __shfl_xor(sm, 16, 64);
    sm += __shfl_xor(sm, 32, 64);
    float mean = sm * (1.f / 128.f);
    float sq = 0.f;
    #pragma unroll
    for (int t = 0; t < 8; ++t)
        #pragma unroll
        for (int r = 0; r < 4; ++r) { float d = acc[t][r] - mean; sq += d * d; }
    sq += __shfl_xor(sq, 16, 64);
    sq += __shfl_xor(sq, 32, 64);
    float rs = rsqrtf(sq * (1.f / 128.f) + 1e-5f);

    if (rowg < M) {
        if (f32out) {
            #pragma unroll
            for (int t = 0; t < 8; ++t) {
                f32x4 g4 = *reinterpret_cast<const f32x4*>(&G[t * 16 + quad * 4]);
                f32x4 b4 = *reinterpret_cast<const f32x4*>(&Bb[t * 16 + quad * 4]);
                f32x4 y;
                #pragma unroll
                for (int r = 0; r < 4; ++r) {
                    float v = (acc[t][r] - mean) * rs * g4[r] + b4[r];
                    y[r] = v > 0.f ? v : 0.f;
                }
                *reinterpret_cast<f32x4*>(&Yf[(size_t)rowg * CDIM + t * 16 + quad * 4]) = y;
            }
        } else {
            #pragma unroll
            for (int t = 0; t < 8; ++t) {
                f32x4 g4 = *reinterpret_cast<const f32x4*>(&G[t * 16 + quad * 4]);
                f32x4 b4 = *reinterpret_cast<const f32x4*>(&Bb[t * 16 + quad * 4]);
                bfvec4 y;
                #pragma unroll
                for (int r = 0; r < 4; ++r) {
                    float v = (acc[t][r] - mean) * rs * g4[r] + b4[r];
                    y[r] = (bf16_t)(v > 0.f ? v : 0.f);
                }
                *reinterpret_cast<bfvec4*>(&Yb[(size_t)rowg * CDIM + t * 16 + quad * 4]) = y;
            }
        }
    }
}

// ---------------------------------------------------------------------------
extern "C" void kernel_launch(void* const* d_in, const int* in_sizes, int n_in,
                              void* d_out, int out_size, void* d_ws, size_t ws_size,
                              hipStream_t stream)
{
    const float* x_user = (const float*)d_in[0];
    const float* x_item = (const float*)d_in[1];
    const float* W_init = (const float*)d_in[2];
    const float* b_init = (const float*)d_in[3];
    const float* mlp_W  = (const float*)d_in[4];
    const float* mlp_b  = (const float*)d_in[5];
    const float* eps    = (const float*)d_in[6];
    const float* ln_g   = (const float*)d_in[7];
    const float* ln_b   = (const float*)d_in[8];
    const int* edge_ui  = (const int*)d_in[9];
    const int* edge_iu  = (const int*)d_in[10];

    float* xuf = (float*)d_out;                     // [N_USER,128]
    float* xif = xuf + (size_t)N_USER * CDIM;       // [N_ITEM,128]

    char* w = (char*)d_ws;
    bf16_t* xub = (bf16_t*)w;                                  // 25.6 MB
    bf16_t* xib = xub + (size_t)N_USER * CDIM;                 // 12.8 MB
    bf16_t* tub = xib + (size_t)N_ITEM * CDIM;                 // 25.6 MB
    bf16_t* tib = tub + (size_t)N_USER * CDIM;                 // 12.8 MB
    int* off_all = (int*)(tib + (size_t)N_ITEM * CDIM);        // N_SEG+1
    int* bsum    = off_all + (N_SEG + 4);
    int* srcbuf  = bsum + (NB_SCAN + 2);                       // 2*NEDGE
    bf16_t* wtg  = (bf16_t*)(srcbuf + 2 * NEDGE);              // 10*16384 bf16

    // rank2 aliases tub: live only hist_rank -> fill_sliced, before gather
    // writes tub. 4.8 MB < 25.6 MB region. 8B-aligned.
    int2* rank2 = (int2*)tub;

    const int gU = (N_USER + 127) / 128;            // 782
    const int gI = (N_ITEM + 127) / 128;            // 391
    const int gSeg = (N_SEG + 256) / 256;
    const int gE = (NEDGE + 255) / 256;             // 2344
    const int gGather = (N_ITEM + 3) / 4 + (N_USER + 3) / 4;

    prep_weights<<<640, 256, 0, stream>>>(W_init, mlp_W, wtg);

    // CSR prep (proven R3 pipeline: rank-based, atomic-free fill)
    zero_i32<<<(N_SEG + 255) / 256, 256, 0, stream>>>(off_all, N_SEG);
    hist_rank<<<gE, 256, 0, stream>>>(edge_ui, edge_iu, off_all, rank2);
    block_scan<<<NB_SCAN, 256, 0, stream>>>(off_all, bsum, N_SEG);
    scan_bsums<<<1, 1024, 0, stream>>>(bsum);
    add_offsets<<<gSeg, 256, 0, stream>>>(off_all, bsum, N_SEG);
    fill_sliced<<<FILL_NCHUNK * 8, 256, 0, stream>>>(edge_ui, edge_iu, off_all, rank2, srcbuf);

    // initial projection -> bf16 ws
    gemm_init<<<gU, 512, 0, stream>>>(x_user, wtg,         b_init,       xub, N_USER);
    gemm_init<<<gI, 512, 0, stream>>>(x_item, wtg + 16384, b_init + 128, xib, N_ITEM);

    for (int l = 0; l < 2; ++l) {
        gather_both<<<gGather, 256, 0, stream>>>(
            xub, xib, eps + 2 * l, off_all, srcbuf, tib, tub);
        mlp_ln_both<<<gI + gU, 512, 0, stream>>>(
            tib, tub, wtg + (size_t)(2 + l * 4) * 16384, mlp_b + l * 4 * 128,
            ln_g + l * 2 * 128, ln_b + l * 2 * 128,
            xib, xub, xif, xuf, (l == 1) ? 1 : 0);
    }
}